// Round 13
// baseline (561.080 us; speedup 1.0000x reference)
//
#include <hip/hip_runtime.h>

typedef __attribute__((ext_vector_type(4))) float f32x4;
typedef unsigned char u8;
typedef unsigned long long u64t;

#define BIG_NEG -1000000000.0f

static constexpr int B_  = 256;
static constexpr int SX_ = 34;
static constexpr int SY_ = 34;
static constexpr int IND = 66;   // IN_DIM
static constexpr int OP_ = 80;   // padded OUT_DIM (65 -> 80)

__device__ __forceinline__ f32x4 mfma_fp8(long a, long b, f32x4 c) {
  return __builtin_amdgcn_mfma_f32_16x16x32_fp8_fp8(a, b, c, 0, 0, 0);
}
__device__ __forceinline__ float sigm(float x)  { return 1.0f / (1.0f + __expf(-x)); }
__device__ __forceinline__ float tanhx(float x) { return 2.0f * sigm(2.0f * x) - 1.0f; }
template <bool HI>
__device__ __forceinline__ unsigned pk2(float a, float b, unsigned old) {
  return __builtin_amdgcn_cvt_pk_fp8_f32(a, b, (int)old, HI);
}
__device__ __forceinline__ void ast32(unsigned* p, unsigned v) {
  __hip_atomic_store(p, v, __ATOMIC_RELAXED, __HIP_MEMORY_SCOPE_AGENT);
}
__device__ __forceinline__ unsigned ald32(const unsigned* p) {
  return __hip_atomic_load(p, __ATOMIC_RELAXED, __HIP_MEMORY_SCOPE_AGENT);
}
// pack 8 consecutive f32 -> 8 fp8 in one long
__device__ __forceinline__ long pack8(const float* p) {
  float4 f0 = *(const float4*)p;
  float4 f1 = *(const float4*)(p + 4);
  unsigned w0 = pk2<false>(f0.x, f0.y, 0); w0 = pk2<true>(f0.z, f0.w, w0);
  unsigned w1 = pk2<false>(f1.x, f1.y, 0); w1 = pk2<true>(f1.z, f1.w, w1);
  return (long)(((u64t)w1 << 32) | (u64t)w0);
}

// ---------------------------------------------------------------------------
// fwd/rev lstm: chunk 32 x 32 units, weights fully VGPR-resident (packed at
// init from f32 inputs). R9/R10-proven structure.
// ---------------------------------------------------------------------------
__device__ __forceinline__ void run_lstm_fr(
    const float* __restrict__ Whh, const float* __restrict__ E,
    bool revr, u8* __restrict__ hall, int b0, int h0,
    unsigned* __restrict__ dom_flags, int myid,
    u8* __restrict__ alds, u8* __restrict__ hT, const u8* __restrict__ tok_small) {
  constexpr int HH = 512;
  const int tid = threadIdx.x;
  const int lane = tid & 63, w = tid >> 6;
  const int lo = lane & 15, q = lane >> 4;
  constexpr int AST2 = HH + 8;
  const int hh = lo & 7;
  const bool hi = (lo >= 8);
  const int hu_e = h0 + w * 8 + hh;

  long breg0[16], breg1[16];
  {
    const float* bf0 = Whh + ((size_t)((lo >> 3) * HH + hu_e)) * HH + q * 8;
    const float* bf1 = Whh + ((size_t)((2 + (lo >> 3)) * HH + hu_e)) * HH + q * 8;
#pragma unroll
    for (int kk = 0; kk < 16; ++kk) {
      breg0[kk] = pack8(bf0 + kk * 32);
      breg1[kk] = pack8(bf1 + kk * 32);
    }
  }
  float creg[4] = {0.f, 0.f, 0.f, 0.f};

  for (int t = 0; t < 34; ++t) {
    f32x4 acc[2][2];
#pragma unroll
    for (int mt = 0; mt < 2; ++mt) {
      acc[mt][0] = (f32x4){0.f, 0.f, 0.f, 0.f};
      acc[mt][1] = (f32x4){0.f, 0.f, 0.f, 0.f};
    }

    if (t > 0) {
      const u8* hsrc = hall + (size_t)t * (256 * HH);
      u64t tmp[8];
#pragma unroll
      for (int ii = 0; ii < 8; ++ii) {
        int idx = tid + ii * 256;
        tmp[ii] = __hip_atomic_load(
            (const u64t*)(hsrc + (size_t)(b0 + (idx >> 6)) * HH + (idx & 63) * 8),
            __ATOMIC_RELAXED, __HIP_MEMORY_SCOPE_AGENT);
      }
#pragma unroll
      for (int ii = 0; ii < 8; ++ii) {
        int idx = tid + ii * 256;
        *(u64t*)&alds[(idx >> 6) * AST2 + (idx & 63) * 8] = tmp[ii];
      }
      __syncthreads();

      const u8* a0p = alds + lo * AST2 + q * 8;
      const u8* a1p = alds + (16 + lo) * AST2 + q * 8;
#pragma unroll
      for (int kk = 0; kk < 16; ++kk) {
        long a0 = *(const long*)(a0p + kk * 32);
        long a1 = *(const long*)(a1p + kk * 32);
        acc[0][0] = mfma_fp8(a0, breg0[kk], acc[0][0]);
        acc[0][1] = mfma_fp8(a0, breg1[kk], acc[0][1]);
        acc[1][0] = mfma_fp8(a1, breg0[kk], acc[1][0]);
        acc[1][1] = mfma_fp8(a1, breg1[kk], acc[1][1]);
      }
    }

    int tpos = revr ? 33 - t : t;
    const u8* tkp = tok_small + tpos * 32;
#pragma unroll
    for (int mt = 0; mt < 2; ++mt) {
      f32x4 t0 = acc[mt][0], t1 = acc[mt][1];
      f32x4 p0, p1;
#pragma unroll
      for (int c2 = 0; c2 < 4; ++c2) {
        p0[c2] = __shfl_xor(t0[c2], 8, 64);
        p1[c2] = __shfl_xor(t1[c2], 8, 64);
      }
#pragma unroll
      for (int rr = 0; rr < 2; ++rr) {
        int r = (hi ? 2 : 0) + rr;
        float iv = hi ? p0[r] : t0[r];
        float fv = hi ? t0[r] : p0[r];
        float gv = hi ? p1[r] : t1[r];
        float ov = hi ? t1[r] : p1[r];
        int m = mt * 16 + q * 4 + r;
        int v = tkp[m];
        const float* e = E + (size_t)v * (4 * HH) + hu_e;
        iv += e[0]; fv += e[HH]; gv += e[2 * HH]; ov += e[3 * HH];
        float cold = creg[mt * 2 + rr];
        float cn = sigm(fv) * cold + sigm(iv) * tanhx(gv);
        float hn = sigm(ov) * tanhx(cn);
        creg[mt * 2 + rr] = cn;
        hT[m * 32 + w * 8 + hh] = (u8)(pk2<false>(hn, hn, 0) & 0xffu);
      }
    }
    __syncthreads();

    {
      int m = tid >> 3, cc = tid & 7;
      unsigned val = *(const unsigned*)&hT[m * 32 + cc * 4];
      u8* hdst = hall + (size_t)(t + 1) * (256 * HH);
      ast32((unsigned*)(hdst + (size_t)(b0 + m) * HH + h0 + cc * 4), val);
    }

    if (t < 33) {
      __asm__ volatile("s_waitcnt vmcnt(0)" ::: "memory");
      __syncthreads();
      unsigned tgt = (unsigned)(t + 1);
      if (tid == 0) ast32(&dom_flags[myid * 32], tgt);
      if (tid < 16) {
        int spin = 0;
        for (;;) {
          unsigned v = ald32(&dom_flags[tid * 32]);
          if (__ballot(v < tgt) == 0) break;
          __builtin_amdgcn_s_sleep(2);
          if (++spin > (1 << 17)) break;
        }
      }
      __syncthreads();
    }
  }
}

// ---------------------------------------------------------------------------
// mod lstm: chunk 16 x 64 units (16 chunks x 16 slices). Wave = 1 m-tile x
// 4 n-tiles {(i,f)|(g,o)} x unit-groups {0-7, 8-15}. Tiles 0/1 VGPR-resident
// (packed at init from f32); tiles 2/3 streamed fp8 from L2.
// ---------------------------------------------------------------------------
__device__ __forceinline__ void run_lstm_mod(
    const float* __restrict__ Whh, const u8* __restrict__ w8,
    const float* __restrict__ E, u8* __restrict__ hall, int b0, int h0,
    unsigned* __restrict__ dom_flags, int myid,
    u8* __restrict__ alds, u8* __restrict__ hT, const u8* __restrict__ tok_small) {
  constexpr int HH = 1024;
  const int tid = threadIdx.x;
  const int lane = tid & 63, w = tid >> 6;
  const int lo = lane & 15, q = lane >> 4;
  constexpr int AST2 = HH + 8;
  const int hh = lo & 7;
  const bool hi = (lo >= 8);
  const int unit0 = h0 + w * 16 + hh;        // unit-group 0 (gg=0)

  long breg0[32], breg1[32];
  {
    const float* bf0 = Whh + ((size_t)((lo >> 3) * HH + unit0)) * HH + q * 8;
    const float* bf1 = Whh + ((size_t)((2 + (lo >> 3)) * HH + unit0)) * HH + q * 8;
#pragma unroll
    for (int kk = 0; kk < 32; ++kk) {
      breg0[kk] = pack8(bf0 + kk * 32);
      breg1[kk] = pack8(bf1 + kk * 32);
    }
  }
  const u8* brow2 = w8 + (size_t)((lo >> 3) * HH + unit0 + 8) * HH + q * 8;
  const u8* brow3 = w8 + (size_t)((2 + (lo >> 3)) * HH + unit0 + 8) * HH + q * 8;

  float creg[4] = {0.f, 0.f, 0.f, 0.f};

  for (int t = 0; t < 34; ++t) {
    f32x4 acc[4];
#pragma unroll
    for (int nt = 0; nt < 4; ++nt) acc[nt] = (f32x4){0.f, 0.f, 0.f, 0.f};

    if (t > 0) {
      const u8* hsrc = hall + (size_t)t * (256 * HH);
      u64t tmp[8];
#pragma unroll
      for (int ii = 0; ii < 8; ++ii) {
        int idx = tid + ii * 256;
        tmp[ii] = __hip_atomic_load(
            (const u64t*)(hsrc + (size_t)(b0 + (idx >> 7)) * HH + (idx & 127) * 8),
            __ATOMIC_RELAXED, __HIP_MEMORY_SCOPE_AGENT);
      }
#pragma unroll
      for (int ii = 0; ii < 8; ++ii) {
        int idx = tid + ii * 256;
        *(u64t*)&alds[(idx >> 7) * AST2 + (idx & 127) * 8] = tmp[ii];
      }
      __syncthreads();

      const u8* a0p = alds + lo * AST2 + q * 8;
#pragma unroll
      for (int kk = 0; kk < 32; ++kk) {
        long a  = *(const long*)(a0p + kk * 32);
        long b2 = *(const long*)(brow2 + kk * 32);
        long b3 = *(const long*)(brow3 + kk * 32);
        acc[0] = mfma_fp8(a, breg0[kk], acc[0]);
        acc[1] = mfma_fp8(a, breg1[kk], acc[1]);
        acc[2] = mfma_fp8(a, b2, acc[2]);
        acc[3] = mfma_fp8(a, b3, acc[3]);
      }
    }

    const u8* tkp = tok_small + t * 16;
#pragma unroll
    for (int gg = 0; gg < 2; ++gg) {
      f32x4 t0 = acc[2 * gg], t1 = acc[2 * gg + 1];
      f32x4 p0, p1;
#pragma unroll
      for (int c2 = 0; c2 < 4; ++c2) {
        p0[c2] = __shfl_xor(t0[c2], 8, 64);
        p1[c2] = __shfl_xor(t1[c2], 8, 64);
      }
#pragma unroll
      for (int rr = 0; rr < 2; ++rr) {
        int r = (hi ? 2 : 0) + rr;
        float iv = hi ? p0[r] : t0[r];
        float fv = hi ? t0[r] : p0[r];
        float gv = hi ? p1[r] : t1[r];
        float ov = hi ? t1[r] : p1[r];
        int m = q * 4 + r;                    // batch row 0..15
        int v = tkp[m];
        int unit = unit0 + gg * 8;
        const float* e = E + (size_t)v * (4 * HH) + unit;
        iv += e[0]; fv += e[HH]; gv += e[2 * HH]; ov += e[3 * HH];
        float cold = creg[gg * 2 + rr];
        float cn = sigm(fv) * cold + sigm(iv) * tanhx(gv);
        float hn = sigm(ov) * tanhx(cn);
        creg[gg * 2 + rr] = cn;
        hT[m * 64 + w * 16 + gg * 8 + hh] = (u8)(pk2<false>(hn, hn, 0) & 0xffu);
      }
    }
    __syncthreads();

    {
      int m = tid >> 4, cc = tid & 15;
      unsigned val = *(const unsigned*)&hT[m * 64 + cc * 4];
      u8* hdst = hall + (size_t)(t + 1) * (256 * HH);
      ast32((unsigned*)(hdst + (size_t)(b0 + m) * HH + h0 + cc * 4), val);
    }

    if (t < 33) {
      __asm__ volatile("s_waitcnt vmcnt(0)" ::: "memory");
      __syncthreads();
      unsigned tgt = (unsigned)(t + 1);
      if (tid == 0) ast32(&dom_flags[myid * 32], tgt);
      if (tid < 16) {
        int spin = 0;
        for (;;) {
          unsigned v = ald32(&dom_flags[tid * 32]);
          if (__ballot(v < tgt) == 0) break;
          __builtin_amdgcn_s_sleep(2);
          if (++spin > (1 << 17)) break;
        }
      }
      __syncthreads();
    }
  }
}

// ---------------------------------------------------------------------------
// mega kernel: prep -> G1 -> lstm -> G2 -> head -> G3 -> pair.
// 512 blocks x 256 thr, 2/CU exact-fit.
// ---------------------------------------------------------------------------
__global__ __launch_bounds__(256, 2) void mega_kernel(
    const float* __restrict__ sources, const float* __restrict__ targets,
    const float* __restrict__ Wih_f, const float* __restrict__ Whh_f, const float* __restrict__ b_f,
    const float* __restrict__ Wih_r, const float* __restrict__ Whh_r, const float* __restrict__ b_r,
    const float* __restrict__ Wih_m, const float* __restrict__ Whh_m, const float* __restrict__ b_m,
    const float* __restrict__ W_sub, const float* __restrict__ b_sub,
    const float* __restrict__ W_ins, const float* __restrict__ b_ins,
    int* __restrict__ tok_x, int* __restrict__ tok_y,
    u8* __restrict__ Wcat, u8* __restrict__ w8_m,
    float* __restrict__ E_f, float* __restrict__ E_r, float* __restrict__ E_m,
    u8* __restrict__ fwd_all, u8* __restrict__ rev_all, u8* __restrict__ y_all,
    float* __restrict__ lx_sub, float* __restrict__ lx_ins,
    float* __restrict__ ly_sub, float* __restrict__ ly_ins,
    float* __restrict__ out, unsigned* __restrict__ flags) {
  __shared__ u8 smem[21504];
  const int blk = blockIdx.x;
  const int tid = threadIdx.x;

  // ================= phase P: prep =================
  if (blk < 68) {                       // decode tokens
    int idx = blk * 256 + tid;
    const int half = SX_ * B_;
    const float* base = (idx < half) ? sources : targets;
    int* outp         = (idx < half) ? tok_x : tok_y;
    int k = (idx < half) ? idx : idx - half;
    const float* p = base + (size_t)k * IND;
    int tok = -1;
    for (int v = 0; v < IND; ++v) if (p[v] > 0.5f) tok = v;
    ast32((unsigned*)&outp[k], (unsigned)tok);
  } else if (blk < 228) {               // pad head W -> fp8
    int widx = (blk - 68) * 256 + tid;
    int row = widx >> 8;
    int wc  = widx & 255;
    int srow = row < 80 ? row : row - 80;
    const float* W = row < 80 ? W_sub : W_ins;
    float f0 = 0.f, f1 = 0.f, f2 = 0.f, f3 = 0.f;
    if (srow < 65) {
      const float* p = W + (size_t)srow * 1024 + wc * 4;
      f0 = p[0]; f1 = p[1]; f2 = p[2]; f3 = p[3];
    }
    unsigned w = pk2<false>(f0, f1, 0);
    w = pk2<true>(f2, f3, w);
    ast32(&((unsigned*)Wcat)[widx], w);
  } else if (blk < 356) {               // build E (LDS transpose)
    float* tile = (float*)smem;         // 64*67*4 = 17152 B
    int tb = blk - 228;
    const float* W; const float* bias; float* E; int H4; int n0;
    if (tb < 32)      { W = Wih_f; bias = b_f; E = E_f; H4 = 2048; n0 = tb * 64; }
    else if (tb < 64) { W = Wih_r; bias = b_r; E = E_r; H4 = 2048; n0 = (tb - 32) * 64; }
    else              { W = Wih_m; bias = b_m; E = E_m; H4 = 4096; n0 = (tb - 64) * 64; }
    const float* s2 = W + (size_t)n0 * IND;
    for (int i = tid; i < 64 * IND; i += 256) {
      int n = i / IND, v = i - n * IND;
      tile[n * 67 + v] = s2[i];
    }
    __syncthreads();
    int lane = tid & 63, w2 = tid >> 6;
    float bl = bias[n0 + lane];
    for (int v = w2; v < 67; v += 4) {
      float val = (v < 66 ? tile[lane * 67 + v] : 0.f) + bl;
      ast32((unsigned*)&E[(size_t)v * H4 + n0 + lane], __float_as_uint(val));
    }
    __syncthreads();
  }
  {                                     // conv Whh_m -> fp8 (ALL blocks)
    const int M4 = 4096 * 1024 / 4;
    int i = blk * 256 + tid;
    const int stride = 512 * 256;
    for (; i < M4; i += stride) {
      float4 f = ((const float4*)Whh_m)[i];
      unsigned w3 = pk2<false>(f.x, f.y, 0);
      w3 = pk2<true>(f.z, f.w, w3);
      ast32(&((unsigned*)w8_m)[i], w3);
    }
  }

  // -------- G1: all prep visible --------
  {
    __asm__ volatile("s_waitcnt vmcnt(0)" ::: "memory");
    __syncthreads();
    if (tid == 0) ast32(&flags[blk * 32], 1u);
    if (tid < 64) {
      int spin = 0;
      for (;;) {
        bool bad = false;
        for (int k = tid; k < 512; k += 64)
          if (ald32(&flags[k * 32]) < 1u) { bad = true; break; }
        if (__ballot(bad) == 0) break;
        __builtin_amdgcn_s_sleep(2);
        if (++spin > (1 << 17)) break;
      }
    }
    __syncthreads();
    __asm__ volatile("" ::: "memory");
  }

  // ================= phase L: lstm =================
  // mod: blocks 0..255 = 16 chunks(16 batch) x 16 slices(64 units)
  // fwd: 256..383 = 8 chunks(32) x 16 slices(32 units); rev: 384..511
  int role, c, s;
  {
    const int b = blk;
    if (b < 256)      { role = 2; c = b >> 4; s = b & 15; }
    else if (b < 384) { int l = b - 256; role = 0; c = l >> 4; s = l & 15; }
    else              { int l = b - 384; role = 1; c = l >> 4; s = l & 15; }
  }
  unsigned* lf = flags + 512 * 32;
  u8* alds = smem;                                   // <= 16640
  u8* hT = smem + 16896;                             // 1024
  u8* tok_small = smem + 17920;                      // 1088

  int dom0, b0;
  if (role == 2) { dom0 = c * 16; b0 = c * 16; }
  else if (role == 0) { dom0 = 256 + c * 16; b0 = c * 32; }
  else { dom0 = 384 + c * 16; b0 = c * 32; }
  {
    const int* tokg = (role == 2) ? tok_y : tok_x;
    const int CS = (role == 2) ? 16 : 32;
    for (int i = tid; i < 34 * CS; i += 256) {
      int t2 = i / CS, m = i - t2 * CS;
      int tk = tokg[t2 * 256 + b0 + m];
      tok_small[i] = (u8)(tk < 0 ? 66 : tk);
    }
  }
  __syncthreads();

  if (role == 2)
    run_lstm_mod(Whh_m, w8_m, E_m, y_all, b0, s * 64, lf + dom0 * 32, s,
                 alds, hT, tok_small);
  else if (role == 0)
    run_lstm_fr(Whh_f, E_f, false, fwd_all, b0, s * 32, lf + dom0 * 32, s,
                alds, hT, tok_small);
  else
    run_lstm_fr(Whh_r, E_r, true, rev_all, b0, s * 32, lf + dom0 * 32, s,
                alds, hT, tok_small);

  // -------- G2: all h slabs visible --------
  {
    __asm__ volatile("s_waitcnt vmcnt(0)" ::: "memory");
    __syncthreads();
    if (tid == 0) ast32(&lf[(dom0 + s) * 32], 34u);
    if (tid < 64) {
      int spin = 0;
      for (;;) {
        bool bad = false;
        for (int k = tid; k < 512; k += 64)
          if (ald32(&lf[k * 32]) < 34u) { bad = true; break; }
        if (__ballot(bad) == 0) break;
        __builtin_amdgcn_s_sleep(2);
        if (++spin > (1 << 17)) break;
      }
    }
    __syncthreads();
    __asm__ volatile("" ::: "memory");
  }

  // ================= phase H: head (544 units over 512 blocks) ==========
  for (int u = blk; u < 544; u += 512) {
    u8* wq = smem;                       // 80*264 = 21120
    const int lane = tid & 63, wave = tid >> 6;
    const int lo = lane & 15, q = lane >> 4;
    bool yside = (u >= 272);
    int rr2 = yside ? u - 272 : u;
    int mb = rr2 >> 1;
    int nh = rr2 & 1;                    // 0 = sub rows 0..79, 1 = ins rows 80..159
    int ij = mb >> 2;
    int bbase = (mb & 3) * 64;

    f32x4 acc[5];
#pragma unroll
    for (int nn = 0; nn < 5; ++nn) acc[nn] = (f32x4){0.f,0.f,0.f,0.f};

    for (int qk = 0; qk < 4; ++qk) {
      long aA[8];
      {
        int row = bbase + wave * 16 + lo;
        const u8* ab;
        if (yside)
          ab = y_all + ((size_t)(ij + 1) * 256 + row) * 1024 + qk * 256 + q * 8;
        else if (qk < 2)
          ab = fwd_all + ((size_t)(ij + 1) * 256 + row) * 512 + qk * 256 + q * 8;
        else
          ab = rev_all + ((size_t)(34 - ij) * 256 + row) * 512 + (qk - 2) * 256 + q * 8;
#pragma unroll
        for (int ki = 0; ki < 8; ++ki) aA[ki] = *(const long*)(ab + ki * 32);
      }
      __syncthreads();
      for (int c8 = tid; c8 < 80 * 32; c8 += 256) {
        int row80 = c8 >> 5, col = (c8 & 31) << 3;
        *(long*)&wq[row80 * 264 + col] =
            *(const long*)&Wcat[(size_t)(nh * 80 + row80) * 1024 + qk * 256 + col];
      }
      __syncthreads();

#pragma unroll
      for (int ki = 0; ki < 8; ++ki) {
#pragma unroll
        for (int nn = 0; nn < 5; ++nn) {
          long bf = *(const long*)&wq[(nn * 16 + lo) * 264 + ki * 32 + q * 8];
          acc[nn] = mfma_fp8(aA[ki], bf, acc[nn]);
        }
      }
    }

#pragma unroll
    for (int nn = 0; nn < 5; ++nn) {
      int n = nn * 16 + lo;
      bool is_sub = (nh == 0);
      float bias = 0.0f;
      if (yside && n < 65) bias = is_sub ? b_sub[n] : b_ins[n];
      float* dst = yside ? (is_sub ? ly_sub : ly_ins) : (is_sub ? lx_sub : lx_ins);
#pragma unroll
      for (int r = 0; r < 4; ++r) {
        int b = bbase + wave * 16 + q * 4 + r;
        ast32((unsigned*)&dst[((size_t)ij * 256 + b) * OP_ + n],
              __float_as_uint(acc[nn][r] + bias));
      }
    }
    __syncthreads();
  }

  // -------- G3: lx/ly visible --------
  unsigned* pf = flags + 1024 * 32;
  {
    __asm__ volatile("s_waitcnt vmcnt(0)" ::: "memory");
    __syncthreads();
    if (tid == 0) ast32(&pf[blk * 32], 1u);
    if (tid < 64) {
      int spin = 0;
      for (;;) {
        bool bad = false;
        for (int k = tid; k < 512; k += 64)
          if (ald32(&pf[k * 32]) < 1u) { bad = true; break; }
        if (__ballot(bad) == 0) break;
        __builtin_amdgcn_s_sleep(2);
        if (++spin > (1 << 17)) break;
      }
    }
    __syncthreads();
    __asm__ volatile("" ::: "memory");
  }

  // ================= phase Pr: pair (544 units over 512 blocks) =========
  {
    const size_t CH = (size_t)SX_ * SY_ * B_;
    const int jq = tid >> 6, bl = tid & 63;
    for (int u = blk; u < 544; u += 512) {
      int hsel = (u >= 272);
      int rem = hsel ? u - 272 : u;
      int i = rem >> 3;
      int bc = (rem >> 1) & 3;
      int jh = rem & 1;
      int b = bc * 64 + bl;
      const float* lx = hsel ? lx_ins : lx_sub;
      const float* ly = hsel ? ly_ins : ly_sub;
      float* outA = out + (hsel ? 0 : CH);
      float* outB = out + (hsel ? 2 * CH : 3 * CH);

      float4 X[17];
      {
        const float4* ps = (const float4*)(lx + ((size_t)i * 256 + b) * OP_);
#pragma unroll
        for (int q2 = 0; q2 < 17; ++q2) X[q2] = ps[q2];
      }
      int tx = tok_x[i * 256 + b];

      for (int j = jh * 17 + jq; j < jh * 17 + 17; j += 4) {
        float4 Y[17];
        {
          const float4* py = (const float4*)(ly + ((size_t)j * 256 + b) * OP_);
#pragma unroll
          for (int q2 = 0; q2 < 17; ++q2) Y[q2] = py[q2];
        }
        int ty = tok_y[j * 256 + b];
        int jn = (j < 33) ? j + 1 : 33;
        int tn = tok_y[jn * 256 + b];
        bool dead = (j == 33) || (tx < 0) || (ty < 0);
        bool ins_ok = (tn != 65);
        int sym = (tn >= 0 && tn < 64) ? tn : -1;

        float v64 = X[16].x + Y[16].x;
        float m = v64;
#pragma unroll
        for (int q2 = 0; q2 < 16; ++q2) {
          m = fmaxf(m, X[q2].x + Y[q2].x);
          m = fmaxf(m, X[q2].y + Y[q2].y);
          m = fmaxf(m, X[q2].z + Y[q2].z);
          m = fmaxf(m, X[q2].w + Y[q2].w);
        }
        float ss = 0.f, vsl = 0.f;
#pragma unroll
        for (int q2 = 0; q2 < 16; ++q2) {
          float v0 = X[q2].x + Y[q2].x;
          float v1 = X[q2].y + Y[q2].y;
          float v2 = X[q2].z + Y[q2].z;
          float v3 = X[q2].w + Y[q2].w;
          ss += __expf(v0 - m) + __expf(v1 - m) + __expf(v2 - m) + __expf(v3 - m);
          int o = q2 * 4;
          vsl = (o == sym) ? v0 : vsl;
          vsl = (o + 1 == sym) ? v1 : vsl;
          vsl = (o + 2 == sym) ? v2 : vsl;
          vsl = (o + 3 == sym) ? v3 : vsl;
        }
        ss += __expf(v64 - m);
        float logZ = m + __logf(ss);
        float valB = v64 - logZ;
        float valA = (sym >= 0) ? (vsl - logZ) : 0.0f;
        size_t obase = ((size_t)i * SY_ + j) * 256 + b;
        outA[obase] = (dead || !ins_ok) ? BIG_NEG : valA;
        outB[obase] = dead ? BIG_NEG : valB;
      }
    }
  }
}

// ---------------------------------------------------------------------------
// launch
// ---------------------------------------------------------------------------
extern "C" void kernel_launch(void* const* d_in, const int* in_sizes, int n_in,
                              void* d_out, int out_size, void* d_ws, size_t ws_size,
                              hipStream_t stream) {
  const float* sources = (const float*)d_in[0];
  const float* targets = (const float*)d_in[1];
  const float* Wih_f = (const float*)d_in[2];
  const float* Whh_f = (const float*)d_in[3];
  const float* b_f   = (const float*)d_in[4];
  const float* Wih_r = (const float*)d_in[5];
  const float* Whh_r = (const float*)d_in[6];
  const float* b_r   = (const float*)d_in[7];
  const float* Wih_m = (const float*)d_in[8];
  const float* Whh_m = (const float*)d_in[9];
  const float* b_m   = (const float*)d_in[10];
  const float* W_sub = (const float*)d_in[11];
  const float* b_sub = (const float*)d_in[12];
  const float* W_ins = (const float*)d_in[13];
  const float* b_ins = (const float*)d_in[14];
  float* out = (float*)d_out;

  char* w = (char*)d_ws;
  constexpr size_t FLAG_SZ = 1536 * 32 * 4;
  constexpr size_t TOK_SZ  = (size_t)SX_ * B_ * 4;
  constexpr size_t WCAT_SZ = (size_t)160 * 1024;
  constexpr size_t W8M_SZ  = (size_t)4096 * 1024;
  constexpr size_t EF_SZ   = (size_t)67 * 2048 * 4;
  constexpr size_t EM_SZ   = (size_t)67 * 4096 * 4;
  constexpr size_t LX_SZ   = (size_t)SX_ * B_ * OP_ * 4;
  constexpr size_t HF_SZ   = (size_t)35 * B_ * 512;
  constexpr size_t HM_SZ   = (size_t)35 * B_ * 1024;

  size_t off = 0;
  unsigned* flags = (unsigned*)(w + off); off += FLAG_SZ;
  int*  tok_x   = (int*)(w + off);  off += TOK_SZ;
  int*  tok_y   = (int*)(w + off);  off += TOK_SZ;
  off = (off + 255) & ~(size_t)255;
  u8*   Wcat    = (u8*)(w + off);   off += WCAT_SZ;
  u8*   w8_m    = (u8*)(w + off);   off += W8M_SZ;
  float* E_f    = (float*)(w + off); off += EF_SZ;
  float* E_r    = (float*)(w + off); off += EF_SZ;
  float* E_m    = (float*)(w + off); off += EM_SZ;
  float* lx_sub = (float*)(w + off); off += LX_SZ;
  float* lx_ins = (float*)(w + off); off += LX_SZ;
  float* ly_sub = (float*)(w + off); off += LX_SZ;
  float* ly_ins = (float*)(w + off); off += LX_SZ;
  u8* fwd_all   = (u8*)(w + off);   off += HF_SZ;
  u8* rev_all   = (u8*)(w + off);   off += HF_SZ;
  u8* y_all     = (u8*)(w + off);   off += HM_SZ;
  (void)ws_size; (void)in_sizes; (void)n_in; (void)out_size;

  (void)hipMemsetAsync(flags, 0, FLAG_SZ, stream);

  mega_kernel<<<512, 256, 0, stream>>>(
      sources, targets,
      Wih_f, Whh_f, b_f,
      Wih_r, Whh_r, b_r,
      Wih_m, Whh_m, b_m,
      W_sub, b_sub, W_ins, b_ins,
      tok_x, tok_y,
      Wcat, w8_m,
      E_f, E_r, E_m,
      fwd_all, rev_all, y_all,
      lx_sub, lx_ins, ly_sub, ly_ins,
      out, flags);
}

// Round 14
// 341.050 us; speedup vs baseline: 1.6452x; 1.6452x over previous
//
#include <hip/hip_runtime.h>

typedef __attribute__((ext_vector_type(4))) float f32x4;
typedef unsigned char u8;
typedef unsigned long long u64t;

#define BIG_NEG -1000000000.0f

static constexpr int B_  = 256;
static constexpr int SX_ = 34;
static constexpr int SY_ = 34;
static constexpr int IND = 66;   // IN_DIM
static constexpr int OP_ = 80;   // padded OUT_DIM (65 -> 80)

__device__ __forceinline__ f32x4 mfma_fp8(long a, long b, f32x4 c) {
  return __builtin_amdgcn_mfma_f32_16x16x32_fp8_fp8(a, b, c, 0, 0, 0);
}
__device__ __forceinline__ float sigm(float x)  { return 1.0f / (1.0f + __expf(-x)); }
__device__ __forceinline__ float tanhx(float x) { return 2.0f * sigm(2.0f * x) - 1.0f; }
template <bool HI>
__device__ __forceinline__ unsigned pk2(float a, float b, unsigned old) {
  return __builtin_amdgcn_cvt_pk_fp8_f32(a, b, (int)old, HI);
}
// pack 8 consecutive f32 -> 8 fp8 in one long
__device__ __forceinline__ long pack8(const float* p) {
  float4 f0 = *(const float4*)p;
  float4 f1 = *(const float4*)(p + 4);
  unsigned w0 = pk2<false>(f0.x, f0.y, 0); w0 = pk2<true>(f0.z, f0.w, w0);
  unsigned w1 = pk2<false>(f1.x, f1.y, 0); w1 = pk2<true>(f1.z, f1.w, w1);
  return (long)(((u64t)w1 << 32) | (u64t)w0);
}

// ---------------------------------------------------------------------------
// fused prep kernel: blocks [0,68) decode | [68,228) pad_head |
// [228,356) build_E | [356,3428) conv_fp8 of Whh_m only (grid-stride)
// ---------------------------------------------------------------------------
__global__ __launch_bounds__(256) void prep_all(
    const float* __restrict__ src, const float* __restrict__ tgt,
    int* __restrict__ tok_x, int* __restrict__ tok_y,
    const float* __restrict__ Wsub, const float* __restrict__ Wins,
    u8* __restrict__ Wcat,
    const float* __restrict__ Wihf, const float* __restrict__ bf,
    const float* __restrict__ Wihr, const float* __restrict__ br,
    const float* __restrict__ Wihm, const float* __restrict__ bm,
    float* __restrict__ Ef, float* __restrict__ Er, float* __restrict__ Em,
    const float* __restrict__ Whm, u8* __restrict__ w8m) {
  __shared__ float tile[64 * 67];
  const int blk = blockIdx.x;
  const int tid = threadIdx.x;

  if (blk < 68) {                       // ---- decode tokens ----
    int idx = blk * 256 + tid;
    const int half = SX_ * B_;
    const float* base = (idx < half) ? src : tgt;
    int* outp         = (idx < half) ? tok_x : tok_y;
    int k = (idx < half) ? idx : idx - half;
    const float* p = base + (size_t)k * IND;
    int tok = -1;
    for (int v = 0; v < IND; ++v) if (p[v] > 0.5f) tok = v;
    outp[k] = tok;
  } else if (blk < 228) {               // ---- pad head W -> fp8 ----
    int widx = (blk - 68) * 256 + tid;
    int row = widx >> 8;
    int wc  = widx & 255;
    int srow = row < 80 ? row : row - 80;
    const float* W = row < 80 ? Wsub : Wins;
    float f0 = 0.f, f1 = 0.f, f2 = 0.f, f3 = 0.f;
    if (srow < 65) {
      const float* p = W + (size_t)srow * 1024 + wc * 4;
      f0 = p[0]; f1 = p[1]; f2 = p[2]; f3 = p[3];
    }
    unsigned w = pk2<false>(f0, f1, 0);
    w = pk2<true>(f2, f3, w);
    ((unsigned*)Wcat)[widx] = w;
  } else if (blk < 356) {               // ---- build E (LDS transpose) ----
    int tb = blk - 228;
    const float* W; const float* bias; float* E; int H4; int n0;
    if (tb < 32)      { W = Wihf; bias = bf; E = Ef; H4 = 2048; n0 = tb * 64; }
    else if (tb < 64) { W = Wihr; bias = br; E = Er; H4 = 2048; n0 = (tb - 32) * 64; }
    else              { W = Wihm; bias = bm; E = Em; H4 = 4096; n0 = (tb - 64) * 64; }
    const float* s2 = W + (size_t)n0 * IND;
    for (int i = tid; i < 64 * IND; i += 256) {
      int n = i / IND, v = i - n * IND;
      tile[n * 67 + v] = s2[i];
    }
    __syncthreads();
    int lane = tid & 63, w2 = tid >> 6;
    float bl = bias[n0 + lane];
    for (int v = w2; v < 67; v += 4) {
      float val = (v < 66 ? tile[lane * 67 + v] : 0.f) + bl;
      E[(size_t)v * H4 + n0 + lane] = val;
    }
  } else {                              // ---- conv Whh_m -> fp8 ----
    const int M4 = 4096 * 1024 / 4;
    int i = (blk - 356) * 256 + tid;
    int stride = 3072 * 256;
    for (; i < M4; i += stride) {
      float4 f = ((const float4*)Whm)[i];
      unsigned w3 = pk2<false>(f.x, f.y, 0);
      w3 = pk2<true>(f.z, f.w, w3);
      ((unsigned*)w8m)[i] = w3;
    }
  }
}

// ---------------------------------------------------------------------------
// persistent LSTM: 512 blocks x 256 thr, 2 blocks/CU (exact-fit grid).
// Block = (batch chunk of 32) x (32 h-units, all 4 gates).
// mod streams fp8 weights (w8_m); fwd/rev pack f32->fp8 into VGPRs at init.
// t=0: h0 == 0 -> skip staging + MFMA (no memset needed).
// h via relaxed agent-scope atomics; ballot flag barrier per chunk-domain.
// ---------------------------------------------------------------------------
__device__ __forceinline__ void run_lstm_mod(
    const u8* __restrict__ w8, const float* __restrict__ E,
    u8* __restrict__ hall, int b0, int h0,
    unsigned* __restrict__ dom_flags, int myid,
    u8* __restrict__ alds, u8* __restrict__ hT, const u8* __restrict__ tok_small) {
  constexpr int HH = 1024;
  constexpr int NS = 32;
  const int tid = threadIdx.x;
  const int lane = tid & 63, w = tid >> 6;
  const int lo = lane & 15, q = lane >> 4;
  constexpr int AST2 = HH + 8;
  constexpr int NK = HH / 32;
  const int hh = lo & 7;
  const bool hi = (lo >= 8);
  const int hu_e = h0 + w * 8 + hh;

  long breg0[NK], breg1[NK];
  {
    const u8* brow0 = w8 + (size_t)((lo >> 3) * HH + hu_e) * HH + q * 8;
    const u8* brow1 = w8 + (size_t)((2 + (lo >> 3)) * HH + hu_e) * HH + q * 8;
#pragma unroll
    for (int kk = 0; kk < NK; ++kk) {
      breg0[kk] = *(const long*)(brow0 + kk * 32);
      breg1[kk] = *(const long*)(brow1 + kk * 32);
    }
  }
  float creg[4] = {0.f, 0.f, 0.f, 0.f};

  for (int t = 0; t < 34; ++t) {
    f32x4 acc[2][2];
#pragma unroll
    for (int mt = 0; mt < 2; ++mt) {
      acc[mt][0] = (f32x4){0.f, 0.f, 0.f, 0.f};
      acc[mt][1] = (f32x4){0.f, 0.f, 0.f, 0.f};
    }

    if (t > 0) {
      const u8* hsrc = hall + (size_t)t * (256 * HH);
      u64t tmp[16];
#pragma unroll
      for (int ii = 0; ii < 16; ++ii) {
        int idx = tid + ii * 256;
        tmp[ii] = __hip_atomic_load(
            (const u64t*)(hsrc + (size_t)(b0 + (idx >> 7)) * HH + (idx & 127) * 8),
            __ATOMIC_RELAXED, __HIP_MEMORY_SCOPE_AGENT);
      }
#pragma unroll
      for (int ii = 0; ii < 16; ++ii) {
        int idx = tid + ii * 256;
        *(u64t*)&alds[(idx >> 7) * AST2 + (idx & 127) * 8] = tmp[ii];
      }
      __syncthreads();

      const u8* a0p = alds + lo * AST2 + q * 8;
      const u8* a1p = alds + (16 + lo) * AST2 + q * 8;
#pragma unroll
      for (int kk = 0; kk < NK; ++kk) {
        long a0 = *(const long*)(a0p + kk * 32);
        long a1 = *(const long*)(a1p + kk * 32);
        acc[0][0] = mfma_fp8(a0, breg0[kk], acc[0][0]);
        acc[0][1] = mfma_fp8(a0, breg1[kk], acc[0][1]);
        acc[1][0] = mfma_fp8(a1, breg0[kk], acc[1][0]);
        acc[1][1] = mfma_fp8(a1, breg1[kk], acc[1][1]);
      }
    }

    const u8* tkp = tok_small + t * 32;
#pragma unroll
    for (int mt = 0; mt < 2; ++mt) {
      f32x4 t0 = acc[mt][0], t1 = acc[mt][1];
      f32x4 p0, p1;
#pragma unroll
      for (int c2 = 0; c2 < 4; ++c2) {
        p0[c2] = __shfl_xor(t0[c2], 8, 64);
        p1[c2] = __shfl_xor(t1[c2], 8, 64);
      }
#pragma unroll
      for (int rr = 0; rr < 2; ++rr) {
        int r = (hi ? 2 : 0) + rr;
        float iv = hi ? p0[r] : t0[r];
        float fv = hi ? t0[r] : p0[r];
        float gv = hi ? p1[r] : t1[r];
        float ov = hi ? t1[r] : p1[r];
        int m = mt * 16 + q * 4 + r;
        int v = tkp[m];
        const float* e = E + (size_t)v * (4 * HH) + hu_e;
        iv += e[0]; fv += e[HH]; gv += e[2 * HH]; ov += e[3 * HH];
        float cold = creg[mt * 2 + rr];
        float cn = sigm(fv) * cold + sigm(iv) * tanhx(gv);
        float hn = sigm(ov) * tanhx(cn);
        creg[mt * 2 + rr] = cn;
        hT[m * 32 + w * 8 + hh] = (u8)(pk2<false>(hn, hn, 0) & 0xffu);
      }
    }
    __syncthreads();

    {
      int m = tid >> 3, cc = tid & 7;
      unsigned val = *(const unsigned*)&hT[m * 32 + cc * 4];
      u8* hdst = hall + (size_t)(t + 1) * (256 * HH);
      __hip_atomic_store((unsigned*)(hdst + (size_t)(b0 + m) * HH + h0 + cc * 4),
                         val, __ATOMIC_RELAXED, __HIP_MEMORY_SCOPE_AGENT);
    }

    if (t < 33) {
      __asm__ volatile("s_waitcnt vmcnt(0)" ::: "memory");
      __syncthreads();
      unsigned tgt = (unsigned)(t + 1);
      if (tid == 0)
        __hip_atomic_store(&dom_flags[myid * 32], tgt,
                           __ATOMIC_RELAXED, __HIP_MEMORY_SCOPE_AGENT);
      if (tid < NS) {
        int spin = 0;
        for (;;) {
          unsigned v = __hip_atomic_load(&dom_flags[tid * 32],
                                         __ATOMIC_RELAXED, __HIP_MEMORY_SCOPE_AGENT);
          if (__ballot(v < tgt) == 0) break;
          __builtin_amdgcn_s_sleep(1);
          if (++spin > (1 << 17)) break;
        }
      }
      __syncthreads();
    }
  }
}

__device__ __forceinline__ void run_lstm_fr(
    const float* __restrict__ Whh, const float* __restrict__ E,
    bool revr, u8* __restrict__ hall, int b0, int h0,
    unsigned* __restrict__ dom_flags, int myid,
    u8* __restrict__ alds, u8* __restrict__ hT, const u8* __restrict__ tok_small) {
  constexpr int HH = 512;
  constexpr int NS = 16;
  const int tid = threadIdx.x;
  const int lane = tid & 63, w = tid >> 6;
  const int lo = lane & 15, q = lane >> 4;
  constexpr int AST2 = HH + 8;
  const int hh = lo & 7;
  const bool hi = (lo >= 8);
  const int hu_e = h0 + w * 8 + hh;

  long breg0[16], breg1[16];
  {
    const float* bf0 = Whh + ((size_t)((lo >> 3) * HH + hu_e)) * HH + q * 8;
    const float* bf1 = Whh + ((size_t)((2 + (lo >> 3)) * HH + hu_e)) * HH + q * 8;
#pragma unroll
    for (int kk = 0; kk < 16; ++kk) {
      breg0[kk] = pack8(bf0 + kk * 32);
      breg1[kk] = pack8(bf1 + kk * 32);
    }
  }
  float creg[4] = {0.f, 0.f, 0.f, 0.f};

  for (int t = 0; t < 34; ++t) {
    f32x4 acc[2][2];
#pragma unroll
    for (int mt = 0; mt < 2; ++mt) {
      acc[mt][0] = (f32x4){0.f, 0.f, 0.f, 0.f};
      acc[mt][1] = (f32x4){0.f, 0.f, 0.f, 0.f};
    }

    if (t > 0) {
      const u8* hsrc = hall + (size_t)t * (256 * HH);
      u64t tmp[8];
#pragma unroll
      for (int ii = 0; ii < 8; ++ii) {
        int idx = tid + ii * 256;
        tmp[ii] = __hip_atomic_load(
            (const u64t*)(hsrc + (size_t)(b0 + (idx >> 6)) * HH + (idx & 63) * 8),
            __ATOMIC_RELAXED, __HIP_MEMORY_SCOPE_AGENT);
      }
#pragma unroll
      for (int ii = 0; ii < 8; ++ii) {
        int idx = tid + ii * 256;
        *(u64t*)&alds[(idx >> 6) * AST2 + (idx & 63) * 8] = tmp[ii];
      }
      __syncthreads();

      const u8* a0p = alds + lo * AST2 + q * 8;
      const u8* a1p = alds + (16 + lo) * AST2 + q * 8;
#pragma unroll
      for (int kk = 0; kk < 16; ++kk) {
        long a0 = *(const long*)(a0p + kk * 32);
        long a1 = *(const long*)(a1p + kk * 32);
        acc[0][0] = mfma_fp8(a0, breg0[kk], acc[0][0]);
        acc[0][1] = mfma_fp8(a0, breg1[kk], acc[0][1]);
        acc[1][0] = mfma_fp8(a1, breg0[kk], acc[1][0]);
        acc[1][1] = mfma_fp8(a1, breg1[kk], acc[1][1]);
      }
    }

    int tpos = revr ? 33 - t : t;
    const u8* tkp = tok_small + tpos * 32;
#pragma unroll
    for (int mt = 0; mt < 2; ++mt) {
      f32x4 t0 = acc[mt][0], t1 = acc[mt][1];
      f32x4 p0, p1;
#pragma unroll
      for (int c2 = 0; c2 < 4; ++c2) {
        p0[c2] = __shfl_xor(t0[c2], 8, 64);
        p1[c2] = __shfl_xor(t1[c2], 8, 64);
      }
#pragma unroll
      for (int rr = 0; rr < 2; ++rr) {
        int r = (hi ? 2 : 0) + rr;
        float iv = hi ? p0[r] : t0[r];
        float fv = hi ? t0[r] : p0[r];
        float gv = hi ? p1[r] : t1[r];
        float ov = hi ? t1[r] : p1[r];
        int m = mt * 16 + q * 4 + r;
        int v = tkp[m];
        const float* e = E + (size_t)v * (4 * HH) + hu_e;
        iv += e[0]; fv += e[HH]; gv += e[2 * HH]; ov += e[3 * HH];
        float cold = creg[mt * 2 + rr];
        float cn = sigm(fv) * cold + sigm(iv) * tanhx(gv);
        float hn = sigm(ov) * tanhx(cn);
        creg[mt * 2 + rr] = cn;
        hT[m * 32 + w * 8 + hh] = (u8)(pk2<false>(hn, hn, 0) & 0xffu);
      }
    }
    __syncthreads();

    {
      int m = tid >> 3, cc = tid & 7;
      unsigned val = *(const unsigned*)&hT[m * 32 + cc * 4];
      u8* hdst = hall + (size_t)(t + 1) * (256 * HH);
      __hip_atomic_store((unsigned*)(hdst + (size_t)(b0 + m) * HH + h0 + cc * 4),
                         val, __ATOMIC_RELAXED, __HIP_MEMORY_SCOPE_AGENT);
    }

    if (t < 33) {
      __asm__ volatile("s_waitcnt vmcnt(0)" ::: "memory");
      __syncthreads();
      unsigned tgt = (unsigned)(t + 1);
      if (tid == 0)
        __hip_atomic_store(&dom_flags[myid * 32], tgt,
                           __ATOMIC_RELAXED, __HIP_MEMORY_SCOPE_AGENT);
      if (tid < NS) {
        int spin = 0;
        for (;;) {
          unsigned v = __hip_atomic_load(&dom_flags[tid * 32],
                                         __ATOMIC_RELAXED, __HIP_MEMORY_SCOPE_AGENT);
          if (__ballot(v < tgt) == 0) break;
          __builtin_amdgcn_s_sleep(1);
          if (++spin > (1 << 17)) break;
        }
      }
      __syncthreads();
    }
  }
}

__global__ __launch_bounds__(256, 2) void lstm_persist(
    const int* __restrict__ tok_x, const int* __restrict__ tok_y,
    const float* __restrict__ E_f, const float* __restrict__ Whh_f,
    const float* __restrict__ E_r, const float* __restrict__ Whh_r,
    const float* __restrict__ E_m, const u8* __restrict__ w8_m,
    u8* __restrict__ fwd_all, u8* __restrict__ rev_all, u8* __restrict__ y_all,
    unsigned* __restrict__ flags) {
  __shared__ u8 alds[32 * 1032];       // 33 KB A-stage (fwd/rev use 32*520)
  __shared__ u8 hT[32 * 32];           // store-transpose buffer
  __shared__ u8 tok_small[34 * 32];    // this block's tokens (66 = none)

  const int b = blockIdx.x;
  int role, c, s;
  if (b < 256)      { role = 2; c = b >> 5; s = b & 31; }          // mod: 256
  else if (b < 384) { int l = b - 256; role = 0; c = l >> 4; s = l & 15; }  // fwd
  else              { int l = b - 384; role = 1; c = l >> 4; s = l & 15; }  // rev

  u8* hall        = role == 0 ? fwd_all : role == 1 ? rev_all : y_all;
  const int* tokg = (role == 2) ? tok_y : tok_x;
  const int b0 = c * 32;
  const int h0 = s * 32;
  const int dom0 = (role == 2) ? c * 32 : (role == 0) ? 256 + c * 16 : 384 + c * 16;

  for (int i = threadIdx.x; i < 34 * 32; i += 256) {
    int t2 = i >> 5, m = i & 31;
    int tk = tokg[t2 * 256 + b0 + m];
    tok_small[i] = (u8)(tk < 0 ? 66 : tk);
  }
  __syncthreads();

  unsigned* dom_flags = flags + dom0 * 32;
  if (role == 2)
    run_lstm_mod(w8_m, E_m, hall, b0, h0, dom_flags, s, alds, hT, tok_small);
  else if (role == 0)
    run_lstm_fr(Whh_f, E_f, false, hall, b0, h0, dom_flags, s, alds, hT, tok_small);
  else
    run_lstm_fr(Whh_r, E_r, true, hall, b0, h0, dom_flags, s, alds, hT, tok_small);
}

// ---------------------------------------------------------------------------
// head: lx = x_emb @ W^T, ly = y_emb @ W^T + b, both heads (W rows 0..159).
// 272 blocks x 256 thr; 64 rows/block (1 m-tile/wave); A-loads before W-stage.
// ---------------------------------------------------------------------------
__global__ __launch_bounds__(256, 1) void head_kernel(
    const u8* __restrict__ fwd_all, const u8* __restrict__ rev_all,
    const u8* __restrict__ y_all, const u8* __restrict__ Wcat,
    const float* __restrict__ b_sub, const float* __restrict__ b_ins,
    float* __restrict__ lx_sub, float* __restrict__ lx_ins,
    float* __restrict__ ly_sub, float* __restrict__ ly_ins) {
  __shared__ u8 wq[160 * 264];   // 42240 B, row pad 264 for bank spread
  const int lane = threadIdx.x & 63, wave = threadIdx.x >> 6;
  const int lo = lane & 15, q = lane >> 4;
  int blk = blockIdx.x;
  bool yside = (blk >= 136);
  int mb = yside ? blk - 136 : blk;
  int ij = mb >> 2;
  int bbase = (mb & 3) * 64;

  f32x4 acc[10];
#pragma unroll
  for (int nn = 0; nn < 10; ++nn) acc[nn] = (f32x4){0.f,0.f,0.f,0.f};

  for (int qk = 0; qk < 4; ++qk) {
    long aA[8];
    {
      int row = bbase + wave * 16 + lo;
      const u8* ab;
      if (yside)
        ab = y_all + ((size_t)(ij + 1) * 256 + row) * 1024 + qk * 256 + q * 8;
      else if (qk < 2)
        ab = fwd_all + ((size_t)(ij + 1) * 256 + row) * 512 + qk * 256 + q * 8;
      else
        ab = rev_all + ((size_t)(34 - ij) * 256 + row) * 512 + (qk - 2) * 256 + q * 8;
#pragma unroll
      for (int ki = 0; ki < 8; ++ki) aA[ki] = *(const long*)(ab + ki * 32);
    }

    for (int c8 = threadIdx.x; c8 < 160 * 32; c8 += 256) {
      int row = c8 >> 5, col = (c8 & 31) << 3;
      *(long*)&wq[row * 264 + col] =
          *(const long*)&Wcat[(size_t)row * 1024 + qk * 256 + col];
    }
    __syncthreads();

#pragma unroll
    for (int ki = 0; ki < 8; ++ki) {
#pragma unroll
      for (int nn = 0; nn < 10; ++nn) {
        long bf = *(const long*)&wq[(nn * 16 + lo) * 264 + ki * 32 + q * 8];
        acc[nn] = mfma_fp8(aA[ki], bf, acc[nn]);
      }
    }
    __syncthreads();
  }

#pragma unroll
  for (int nn = 0; nn < 10; ++nn) {
    bool is_sub = (nn < 5);
    int n = (is_sub ? nn : nn - 5) * 16 + lo;
    float bias = 0.0f;
    if (yside && n < 65) bias = is_sub ? b_sub[n] : b_ins[n];
    float* dst = yside ? (is_sub ? ly_sub : ly_ins) : (is_sub ? lx_sub : lx_ins);
#pragma unroll
    for (int r = 0; r < 4; ++r) {
      int b = bbase + wave * 16 + q * 4 + r;
      dst[((size_t)ij * 256 + b) * OP_ + n] = acc[nn][r] + bias;
    }
  }
}

// ---------------------------------------------------------------------------
// pair: split by HEAD. grid 272 = head{sub,ins} x 34 i x 4 b-chunks;
// block 256 thr (64 b x 4 j-lanes). X (one head) in regs.
//   sub pass -> ch1 (sub), ch3 (del);  ins pass -> ch0 (ins), ch2 (end)
// ---------------------------------------------------------------------------
__device__ __forceinline__ void lse_one(const float4* __restrict__ X,
                                        const float* __restrict__ py, int sym,
                                        float& logZ, float& v64, float& vs) {
  float v[68];
  const float4* py4 = (const float4*)py;
#pragma unroll
  for (int q = 0; q < 17; ++q) {
    float4 yb = py4[q];
    v[4 * q + 0] = X[q].x + yb.x;
    v[4 * q + 1] = X[q].y + yb.y;
    v[4 * q + 2] = X[q].z + yb.z;
    v[4 * q + 3] = X[q].w + yb.w;
  }
  float m = v[0];
#pragma unroll
  for (int o = 1; o < 65; ++o) m = fmaxf(m, v[o]);
  float s = 0.0f, vsl = 0.0f;
#pragma unroll
  for (int o = 0; o < 65; ++o) {
    s += __expf(v[o] - m);
    if (o < 64) vsl = (o == sym) ? v[o] : vsl;
  }
  logZ = m + __logf(s);
  v64 = v[64];
  vs = vsl;
}

__global__ __launch_bounds__(256, 1) void pair_kernel(
    const int* __restrict__ tok_x, const int* __restrict__ tok_y,
    const float* __restrict__ lx_sub, const float* __restrict__ lx_ins,
    const float* __restrict__ ly_sub, const float* __restrict__ ly_ins,
    float* __restrict__ out) {
  const int hsel = blockIdx.x >= 136;
  const int rem = hsel ? blockIdx.x - 136 : blockIdx.x;
  const int i = rem >> 2;
  const int bc = rem & 3;
  const int jq = threadIdx.x >> 6;
  const int bl = threadIdx.x & 63;
  const int b = bc * 64 + bl;
  const size_t CH = (size_t)SX_ * SY_ * B_;
  const float* lx = hsel ? lx_ins : lx_sub;
  const float* ly = hsel ? ly_ins : ly_sub;
  float* outA = out + (hsel ? 0 : CH);
  float* outB = out + (hsel ? 2 * CH : 3 * CH);

  float4 X[17];
  {
    const float4* ps = (const float4*)(lx + ((size_t)i * 256 + b) * OP_);
#pragma unroll
    for (int q = 0; q < 17; ++q) X[q] = ps[q];
  }
  int tx = tok_x[i * 256 + b];

  for (int j = jq; j < 34; j += 4) {
    size_t obase = ((size_t)i * SY_ + j) * 256 + b;
    bool dead = (j == SY_ - 1) || (tx < 0);
    if (!dead) {
      int ty = tok_y[j * 256 + b];
      if (ty < 0) dead = true;
    }
    if (dead) {
      outA[obase] = BIG_NEG;
      outB[obase] = BIG_NEG;
      continue;
    }
    int tn = tok_y[(j + 1) * 256 + b];
    bool ins_ok = (tn != 65);
    int sym = (tn >= 0 && tn < 64) ? tn : -1;

    float logZ, v64, vs;
    lse_one(X, ly + ((size_t)j * 256 + b) * OP_, sym, logZ, v64, vs);
    float valB = v64 - logZ;
    float valA = (sym >= 0) ? (vs - logZ) : 0.0f;
    outA[obase] = ins_ok ? valA : BIG_NEG;
    outB[obase] = valB;
  }
}

// ---------------------------------------------------------------------------
// launch
// ---------------------------------------------------------------------------
extern "C" void kernel_launch(void* const* d_in, const int* in_sizes, int n_in,
                              void* d_out, int out_size, void* d_ws, size_t ws_size,
                              hipStream_t stream) {
  const float* sources = (const float*)d_in[0];
  const float* targets = (const float*)d_in[1];
  const float* Wih_f = (const float*)d_in[2];
  const float* Whh_f = (const float*)d_in[3];
  const float* b_f   = (const float*)d_in[4];
  const float* Wih_r = (const float*)d_in[5];
  const float* Whh_r = (const float*)d_in[6];
  const float* b_r   = (const float*)d_in[7];
  const float* Wih_m = (const float*)d_in[8];
  const float* Whh_m = (const float*)d_in[9];
  const float* b_m   = (const float*)d_in[10];
  const float* W_sub = (const float*)d_in[11];
  const float* b_sub = (const float*)d_in[12];
  const float* W_ins = (const float*)d_in[13];
  const float* b_ins = (const float*)d_in[14];
  float* out = (float*)d_out;

  char* w = (char*)d_ws;
  constexpr size_t FLAG_SZ = 512 * 32 * 4;                  // 64 KB, 128B-spread
  constexpr size_t TOK_SZ  = (size_t)SX_ * B_ * 4;
  constexpr size_t WCAT_SZ = (size_t)160 * 1024;
  constexpr size_t W8M_SZ  = (size_t)4096 * 1024;
  constexpr size_t EF_SZ   = (size_t)67 * 2048 * 4;
  constexpr size_t EM_SZ   = (size_t)67 * 4096 * 4;
  constexpr size_t LX_SZ   = (size_t)SX_ * B_ * OP_ * 4;
  constexpr size_t HF_SZ   = (size_t)35 * B_ * 512;
  constexpr size_t HM_SZ   = (size_t)35 * B_ * 1024;

  size_t off = 0;
  unsigned* flags = (unsigned*)(w + off); off += FLAG_SZ;
  int*  tok_x   = (int*)(w + off);  off += TOK_SZ;
  int*  tok_y   = (int*)(w + off);  off += TOK_SZ;
  off = (off + 255) & ~(size_t)255;
  u8*   Wcat    = (u8*)(w + off);   off += WCAT_SZ;
  u8*   w8_m    = (u8*)(w + off);   off += W8M_SZ;
  float* E_f    = (float*)(w + off); off += EF_SZ;
  float* E_r    = (float*)(w + off); off += EF_SZ;
  float* E_m    = (float*)(w + off); off += EM_SZ;
  float* lx_sub = (float*)(w + off); off += LX_SZ;
  float* lx_ins = (float*)(w + off); off += LX_SZ;
  float* ly_sub = (float*)(w + off); off += LX_SZ;
  float* ly_ins = (float*)(w + off); off += LX_SZ;
  u8* fwd_all   = (u8*)(w + off);   off += HF_SZ;
  u8* rev_all   = (u8*)(w + off);   off += HF_SZ;
  u8* y_all     = (u8*)(w + off);   off += HM_SZ;
  (void)ws_size; (void)in_sizes; (void)n_in; (void)out_size;

  (void)hipMemsetAsync(flags, 0, FLAG_SZ, stream);

  prep_all<<<3428, 256, 0, stream>>>(
      sources, targets, tok_x, tok_y,
      W_sub, W_ins, Wcat,
      Wih_f, b_f, Wih_r, b_r, Wih_m, b_m, E_f, E_r, E_m,
      Whh_m, w8_m);

  lstm_persist<<<512, 256, 0, stream>>>(
      tok_x, tok_y,
      E_f, Whh_f,
      E_r, Whh_r,
      E_m, w8_m,
      fwd_all, rev_all, y_all, flags);

  head_kernel<<<272, 256, 0, stream>>>(fwd_all, rev_all, y_all, Wcat,
                                       b_sub, b_ins, lx_sub, lx_ins, ly_sub, ly_ins);

  pair_kernel<<<272, 256, 0, stream>>>(tok_x, tok_y, lx_sub, lx_ins,
                                       ly_sub, ly_ins, out);
}